// Round 4
// baseline (112.860 us; speedup 1.0000x reference)
//
#include <hip/hip_runtime.h>

// UnarySqrt bitstream scan: L=64 steps over N=2^20 independent columns.
// R3: 2 columns/thread (dwordx2, 8B/lane) -> 8192 waves = 8 waves/SIMD (full
// occupancy) to double outstanding memory parallelism. State in registers,
// full unroll + distance-1 nontemporal prefetch.
// Memory-bound: 536.9 MB total traffic, floor ~85 us at 6.3 TB/s copy ceiling.

#define STEPS 64

typedef float v2f __attribute__((ext_vector_type(2)));

__global__ __launch_bounds__(256, 8)
void unary_sqrt_kernel(const float* __restrict__ bits,
                       float* __restrict__ out, int N) {
    const int t  = blockIdx.x * blockDim.x + threadIdx.x;
    const int n2 = t * 2;
    if (n2 >= N) return;

    const v2f* __restrict__ in2  = reinterpret_cast<const v2f*>(bits + n2);
    v2f* __restrict__       out2 = reinterpret_cast<v2f*>(out + n2);
    const int stride2 = N >> 1;   // row stride in 8B units

    int cnt[2] = {0, 0};
    int sr [2] = {1, 1};   // historic quotient init = 1
    int acc[2] = {0, 0};

    v2f v = __builtin_nontemporal_load(&in2[0]);

    #pragma unroll
    for (int l = 0; l < STEPS; ++l) {
        v2f vn = v;
        if (l + 1 < STEPS)
            vn = __builtin_nontemporal_load(&in2[(size_t)(l + 1) * stride2]);

        v2f ov;
        #pragma unroll
        for (int j = 0; j < 2; ++j) {
            const int x       = v[j] > 0.5f;           // input bit
            const int emit_en = (x ^ 1) & (acc[j] > 0);
            const int ot      = x | emit_en;           // output bit
            const int cnm     = (cnt[j] != 0);         // cnt not min
            const int cnx     = (cnt[j] != 3);         // cnt not max
            // out==1: release from sync buffer; out==0: try to buffer
            const int q = ot ? cnm : sr[j];
            cnt[j] += ot ? -cnm : cnx;
            sr[j]   = ot ? q : sr[j];                  // sr takes q only when divisor==1
            acc[j]  = min(max(acc[j] + q - emit_en, 0), 7);
            ov[j] = (float)ot;
        }
        __builtin_nontemporal_store(ov, &out2[(size_t)l * stride2]);
        v = vn;
    }
}

extern "C" void kernel_launch(void* const* d_in, const int* in_sizes, int n_in,
                              void* d_out, int out_size, void* d_ws, size_t ws_size,
                              hipStream_t stream) {
    const float* bits = (const float*)d_in[0];
    float* out = (float*)d_out;
    const int total = in_sizes[0];        // L * N
    const int N = total / STEPS;

    const int threads = 256;
    const int blocks  = (N / 2 + threads - 1) / threads;
    unary_sqrt_kernel<<<blocks, threads, 0, stream>>>(bits, out, N);
}

// Round 5
// 101.914 us; speedup vs baseline: 1.1074x; 1.1074x over previous
//
#include <hip/hip_runtime.h>

// UnarySqrt bitstream scan: L=64 steps over N=2^20 independent columns.
// R4: back to 4 cols/thread (16B/lane, best coalescing; R3's 8B/lane
// regressed 15%). Deepen prefetch to distance 2 (two 16B loads in flight
// per wave) to raise MLP against ~900cy HBM latency. Full unroll keeps the
// 2-slot pipeline statically indexed (no scratch).
// Memory-bound: 536.9 MB total traffic, floor ~85 us at 6.3 TB/s copy ceiling.

#define STEPS 64

typedef float v4f __attribute__((ext_vector_type(4)));

__global__ __launch_bounds__(256)
void unary_sqrt_kernel(const float* __restrict__ bits,
                       float* __restrict__ out, int N) {
    const int t  = blockIdx.x * blockDim.x + threadIdx.x;
    const int n4 = t * 4;
    if (n4 >= N) return;

    const v4f* __restrict__ in4  = reinterpret_cast<const v4f*>(bits + n4);
    v4f* __restrict__       out4 = reinterpret_cast<v4f*>(out + n4);
    const int stride4 = N >> 2;   // row stride in 16B units

    int cnt[4] = {0, 0, 0, 0};
    int sr [4] = {1, 1, 1, 1};   // historic quotient init = 1
    int acc[4] = {0, 0, 0, 0};

    // 2-deep prefetch pipeline; fully unrolled loop -> static indexing.
    v4f pf0 = __builtin_nontemporal_load(&in4[0]);
    v4f pf1 = __builtin_nontemporal_load(&in4[(size_t)stride4]);

    #pragma unroll
    for (int l = 0; l < STEPS; ++l) {
        const v4f v = (l & 1) ? pf1 : pf0;
        if (l + 2 < STEPS) {
            const v4f nv = __builtin_nontemporal_load(&in4[(size_t)(l + 2) * stride4]);
            if (l & 1) pf1 = nv; else pf0 = nv;
        }

        v4f ov;
        #pragma unroll
        for (int j = 0; j < 4; ++j) {
            const int x       = v[j] > 0.5f;           // input bit
            const int emit_en = (x ^ 1) & (acc[j] > 0);
            const int ot      = x | emit_en;           // output bit
            const int cnm     = (cnt[j] != 0);         // cnt not min
            const int cnx     = (cnt[j] != 3);         // cnt not max
            // out==1: release from sync buffer; out==0: try to buffer
            const int q = ot ? cnm : sr[j];
            cnt[j] += ot ? -cnm : cnx;
            sr[j]   = ot ? q : sr[j];                  // sr takes q only when divisor==1
            acc[j]  = min(max(acc[j] + q - emit_en, 0), 7);
            ov[j] = (float)ot;
        }
        __builtin_nontemporal_store(ov, &out4[(size_t)l * stride4]);
    }
}

extern "C" void kernel_launch(void* const* d_in, const int* in_sizes, int n_in,
                              void* d_out, int out_size, void* d_ws, size_t ws_size,
                              hipStream_t stream) {
    const float* bits = (const float*)d_in[0];
    float* out = (float*)d_out;
    const int total = in_sizes[0];        // L * N
    const int N = total / STEPS;

    const int threads = 256;
    const int blocks  = (N / 4 + threads - 1) / threads;
    unary_sqrt_kernel<<<blocks, threads, 0, stream>>>(bits, out, N);
}